// Round 1
// 172.613 us; speedup vs baseline: 1.0354x; 1.0354x over previous
//
#include <hip/hip_runtime.h>

#define F_DIM 128
#define TE_DIM 32
#define DD 160
#define NB 4096
#define KK 64
#define ROWS 4
#define LD 164        // padded fp32 LDS row stride (164 % 32 = 4)
#define TE_STRIDE 36  // padded half stride: 18 dwords/row, 18*lane mod 32 -> 2-way max (free)

// ws layout (float offsets)
#define WS_M   0          // [160][160]  (Wk^T Wq) / sqrt(160)
#define WS_V2  25600      // [160][160]  out_w @ Wv
#define WS_C   51200      // [160]       (Wk^T bq) / sqrt(160)
#define WS_U   51360      // [160]       (Wq^T bk) / sqrt(160)
#define WS_B2  51520      // [160]       out_w @ bv + out_b
#define WS_S0  51680      // [1]         (bq . bk) / sqrt(160)
#define WS_TOT 51681

__device__ __forceinline__ float dot4acc(const float4 w, const float4 v, float a) {
    a = fmaf(w.x, v.x, a);
    a = fmaf(w.y, v.y, a);
    a = fmaf(w.z, v.z, a);
    a = fmaf(w.w, v.w, a);
    return a;
}

__device__ __forceinline__ float wave_max(float v) {
    #pragma unroll
    for (int off = 32; off > 0; off >>= 1) v = fmaxf(v, __shfl_xor(v, off, 64));
    return v;
}
__device__ __forceinline__ float wave_sum(float v) {
    #pragma unroll
    for (int off = 32; off > 0; off >>= 1) v += __shfl_xor(v, off, 64);
    return v;
}

// Block-cooperative GEMV: vout[r][d] = sum_f W[d][f]*vin[r][f] + bias[d]
// r = tid&3, dl = tid>>2; lanes 4t..4t+3 read identical weight addresses
// -> coalescer dedups -> W read once per block.
__device__ __forceinline__ void gemv_rows(
    const float* __restrict__ W, const float* __restrict__ bias,
    const float (*vin)[LD], float (*vout)[LD], int tid)
{
    const int r  = tid & 3;
    const int dl = tid >> 2;  // 0..63, wave-uniform dl<32 split
    const float4* v4 = (const float4*)vin[r];
    const float4* w0 = (const float4*)(W + (long)dl * DD);
    const float4* w1 = (const float4*)(W + (long)(dl + 64) * DD);
    float a0 = bias[dl];
    float a1 = bias[dl + 64];
    if (dl < 32) {
        const float4* w2 = (const float4*)(W + (long)(dl + 128) * DD);
        float a2 = bias[dl + 128];
        #pragma unroll 8
        for (int f = 0; f < 40; ++f) {
            const float4 v = v4[f];
            a0 = dot4acc(w0[f], v, a0);
            a1 = dot4acc(w1[f], v, a1);
            a2 = dot4acc(w2[f], v, a2);
        }
        vout[r][dl]       = a0;
        vout[r][dl + 64]  = a1;
        vout[r][dl + 128] = a2;
    } else {
        #pragma unroll 8
        for (int f = 0; f < 40; ++f) {
            const float4 v = v4[f];
            a0 = dot4acc(w0[f], v, a0);
            a1 = dot4acc(w1[f], v, a1);
        }
        vout[r][dl]      = a0;
        vout[r][dl + 64] = a1;
    }
}

// ---------------- setup: fold weight matrices (runs every launch) ----------
// One block per output ROW of each 160x160 product:
//   blocks [0,160)    : M[e][f]  = inv * sum_d Wk[d][e] * Wq[d][f]   (e = blk)
//   blocks [160,320)  : V2[i][f] = sum_d ow[i][d] * Wv[d][f]         (i = blk-160)
//   block  320        : C[e]     = inv * sum_d Wk[d][e] * bq[d]
//   block  321        : U[f]     = inv * sum_d Wq[d][f] * bk[d]
//   block  322        : B2[i]    = ob[i] + sum_d ow[i][d] * bv[d];  s0 (wave 3)
// Block-uniform operand staged in LDS (broadcast); streamed operand coalesced;
// 4 independent accumulators + unroll -> ~16 loads in flight per thread.
__global__ __launch_bounds__(256)
void setup_kernel(const float* __restrict__ ipw, const float* __restrict__ ipb,
                  const float* __restrict__ ow,  const float* __restrict__ ob,
                  float* __restrict__ ws)
{
    const int blk = blockIdx.x;
    const int t   = threadIdx.x;
    const float inv = 0.07905694150420949f;  // 1/sqrt(160)

    __shared__ float s_vec[DD];

    if (blk < DD) {
        // ---- M row e = blk ----
        const float* wk = ipw + DD * DD;
        if (t < DD) s_vec[t] = wk[(long)t * DD + blk];   // column of Wk (uncoalesced, one-shot)
        __syncthreads();
        if (t < DD) {
            float a0 = 0.f, a1 = 0.f, a2 = 0.f, a3 = 0.f;
            #pragma unroll 4
            for (int d = 0; d < DD; d += 4) {
                a0 = fmaf(s_vec[d],     ipw[(long)d * DD + t],       a0);
                a1 = fmaf(s_vec[d + 1], ipw[(long)(d + 1) * DD + t], a1);
                a2 = fmaf(s_vec[d + 2], ipw[(long)(d + 2) * DD + t], a2);
                a3 = fmaf(s_vec[d + 3], ipw[(long)(d + 3) * DD + t], a3);
            }
            ws[WS_M + blk * DD + t] = (a0 + a1 + a2 + a3) * inv;
        }
    } else if (blk < 2 * DD) {
        // ---- V2 row i = blk - 160 ----
        const int i = blk - DD;
        const float* wv = ipw + 2 * DD * DD;
        if (t < DD) s_vec[t] = ow[(long)i * DD + t];     // row of out_w (coalesced)
        __syncthreads();
        if (t < DD) {
            float a0 = 0.f, a1 = 0.f, a2 = 0.f, a3 = 0.f;
            #pragma unroll 4
            for (int d = 0; d < DD; d += 4) {
                a0 = fmaf(s_vec[d],     wv[(long)d * DD + t],       a0);
                a1 = fmaf(s_vec[d + 1], wv[(long)(d + 1) * DD + t], a1);
                a2 = fmaf(s_vec[d + 2], wv[(long)(d + 2) * DD + t], a2);
                a3 = fmaf(s_vec[d + 3], wv[(long)(d + 3) * DD + t], a3);
            }
            ws[WS_V2 + i * DD + t] = a0 + a1 + a2 + a3;
        }
    } else if (blk == 2 * DD) {
        // ---- C[e] = inv * sum_d Wk[d][e] * bq[d] ----
        const float* wk = ipw + DD * DD;
        if (t < DD) s_vec[t] = ipb[t];                   // bq
        __syncthreads();
        if (t < DD) {
            float a0 = 0.f, a1 = 0.f, a2 = 0.f, a3 = 0.f;
            #pragma unroll 4
            for (int d = 0; d < DD; d += 4) {
                a0 = fmaf(s_vec[d],     wk[(long)d * DD + t],       a0);
                a1 = fmaf(s_vec[d + 1], wk[(long)(d + 1) * DD + t], a1);
                a2 = fmaf(s_vec[d + 2], wk[(long)(d + 2) * DD + t], a2);
                a3 = fmaf(s_vec[d + 3], wk[(long)(d + 3) * DD + t], a3);
            }
            ws[WS_C + t] = (a0 + a1 + a2 + a3) * inv;
        }
    } else if (blk == 2 * DD + 1) {
        // ---- U[f] = inv * sum_d Wq[d][f] * bk[d] ----
        if (t < DD) s_vec[t] = ipb[DD + t];              // bk
        __syncthreads();
        if (t < DD) {
            float a0 = 0.f, a1 = 0.f, a2 = 0.f, a3 = 0.f;
            #pragma unroll 4
            for (int d = 0; d < DD; d += 4) {
                a0 = fmaf(s_vec[d],     ipw[(long)d * DD + t],       a0);
                a1 = fmaf(s_vec[d + 1], ipw[(long)(d + 1) * DD + t], a1);
                a2 = fmaf(s_vec[d + 2], ipw[(long)(d + 2) * DD + t], a2);
                a3 = fmaf(s_vec[d + 3], ipw[(long)(d + 3) * DD + t], a3);
            }
            ws[WS_U + t] = (a0 + a1 + a2 + a3) * inv;
        }
    } else {
        // ---- B2[i] = ob[i] + sum_d ow[i][d] * bv[d]  (threads 0..159) ----
        // ---- s0 = inv * sum_d bq[d]*bk[d]            (wave 3, shuffle-reduced) ----
        if (t < DD) s_vec[t] = ipb[2 * DD + t];          // bv
        __syncthreads();
        if (t < DD) {
            const float* owr = ow + (long)t * DD;        // per-lane row walk; L1 line reuse
            float a0 = 0.f, a1 = 0.f, a2 = 0.f, a3 = 0.f;
            #pragma unroll 4
            for (int d = 0; d < DD; d += 4) {
                a0 = fmaf(s_vec[d],     owr[d],     a0);
                a1 = fmaf(s_vec[d + 1], owr[d + 1], a1);
                a2 = fmaf(s_vec[d + 2], owr[d + 2], a2);
                a3 = fmaf(s_vec[d + 3], owr[d + 3], a3);
            }
            ws[WS_B2 + t] = ob[t] + (a0 + a1 + a2 + a3);
        }
        if (t >= 192) {
            const int lane = t - 192;
            float p = ipb[lane] * ipb[DD + lane];
            p = fmaf(ipb[lane + 64], ipb[DD + lane + 64], p);
            if (lane < 32) p = fmaf(ipb[lane + 128], ipb[DD + lane + 128], p);
            const float s = wave_sum(p);
            if (lane == 0) ws[WS_S0] = s * inv;
        }
    }
}

// ---------------- main ------------------------------------------------------
__global__ __launch_bounds__(256, 4)
void structure_learner_kernel(
    const float* __restrict__ x,
    const int*   __restrict__ target_node_ids,
    const int*   __restrict__ target_node_times,
    const int*   __restrict__ neighbor_ids,
    const int*   __restrict__ edge_time,
    const float* __restrict__ edge_weight,
    const float* __restrict__ gumbel_u,
    const float* __restrict__ te_w,
    const float* __restrict__ te_b,
    const float* __restrict__ mlp_w,
    const float* __restrict__ mlp_b,
    const float* __restrict__ ws,
    float* __restrict__ out_ao,
    float* __restrict__ out_new,
    float* __restrict__ out_mask)
{
    __shared__ __attribute__((aligned(16))) float s_qin[ROWS][LD];
    __shared__ __attribute__((aligned(16))) float s_qt[ROWS][LD];
    __shared__ __attribute__((aligned(16))) float s_wkv[ROWS][LD];
    __shared__ __attribute__((aligned(16))) float s_ao[ROWS][LD];
    __shared__ float s_attnw[ROWS][KK];
    __shared__ int   s_nid[ROWS][KK];
    __shared__ __attribute__((aligned(4))) _Float16 s_te[ROWS][KK][TE_STRIDE];

    const int tid  = threadIdx.x;
    const int wr   = tid >> 6;   // wave == row
    const int lane = tid & 63;
    const int b    = blockIdx.x * ROWS + wr;

    const float* Mw = ws + WS_M;
    const float* V2 = ws + WS_V2;
    const float* Cv = ws + WS_C;
    const float* Uv = ws + WS_U;
    const float* B2 = ws + WS_B2;
    const float  s0 = ws[WS_S0];

    // ---- P0: meta + q_in + te table (each cos exactly once; lane = k) ----
    {
        s_nid[wr][lane] = neighbor_ids[(long)b * KK + lane];
        const float etv = (float)edge_time[(long)b * KK + lane];
        const int tn = target_node_ids[b];
        const float2 tx = *(const float2*)(x + (long)tn * F_DIM + lane * 2);
        s_qin[wr][lane * 2]     = tx.x;
        s_qin[wr][lane * 2 + 1] = tx.y;
        if (lane < TE_DIM) {
            const float tt = (float)target_node_times[b];
            s_qin[wr][F_DIM + lane] = cosf(tt * te_w[lane] + te_b[lane]);
        }
        // te table row for k = lane: 16 packed dword writes
        #pragma unroll
        for (int jj = 0; jj < 16; ++jj) {
            union { _Float16 h[2]; unsigned u; } pk;
            pk.h[0] = (_Float16)cosf(etv * te_w[2 * jj]     + te_b[2 * jj]);
            pk.h[1] = (_Float16)cosf(etv * te_w[2 * jj + 1] + te_b[2 * jj + 1]);
            *(unsigned*)&s_te[wr][lane][2 * jj] = pk.u;
        }
    }
    __syncthreads();

    // ---- P1: q_tilde = M @ q_in + c (256 threads, 4 rows) ----
    gemv_rows(Mw, Cv, s_qin, s_qt, tid);
    __syncthreads();

    // ---- P2: scores + softmax (wave per row, lane = k) ----
    float aw;
    {
        // sbk = q_in . U + s0 (folded q . bk term)
        float p = s_qin[wr][lane] * Uv[lane];
        p = fmaf(s_qin[wr][lane + 64], Uv[lane + 64], p);
        if (lane < 32) p = fmaf(s_qin[wr][128 + lane], Uv[128 + lane], p);
        const float sbk = wave_sum(p) + s0;

        const int nidk = s_nid[wr][lane];
        const float4* xr  = (const float4*)(x + (long)nidk * F_DIM);
        const float4* qt4 = (const float4*)s_qt[wr];
        float acc = 0.f;
        #pragma unroll 8
        for (int f = 0; f < F_DIM / 4; ++f)
            acc = dot4acc(xr[f], qt4[f], acc);
        const float* qte = s_qt[wr] + F_DIM;
        #pragma unroll
        for (int jj = 0; jj < 16; ++jj) {
            union { _Float16 h[2]; unsigned u; } pk;
            pk.u = *(const unsigned*)&s_te[wr][lane][2 * jj];
            acc = fmaf(qte[2 * jj],     (float)pk.h[0], acc);
            acc = fmaf(qte[2 * jj + 1], (float)pk.h[1], acc);
        }
        const float sc = acc + sbk;
        const float m = wave_max(sc);
        const float e = expf(sc - m);
        const float l = wave_sum(e);
        aw = e / l;
        s_attnw[wr][lane] = aw;  // produced & consumed by this wave — no barrier
    }

    // ---- P3: wkv = sum_k attn_w[k] * kv[k] (wave per row, lane = feat pair) ----
    {
        float ax = 0.f, ay = 0.f, at = 0.f;
        const float* xb = x + lane * 2;
        const int lte = lane & 31;
        #pragma unroll 8
        for (int k = 0; k < KK; ++k) {
            const float wgt = s_attnw[wr][k];
            const int   nid = s_nid[wr][k];
            const float2 xv = *(const float2*)(xb + (long)nid * F_DIM);
            ax = fmaf(wgt, xv.x, ax);
            ay = fmaf(wgt, xv.y, ay);
            at = fmaf(wgt, (float)s_te[wr][k][lte], at);  // broadcast pairs, free
        }
        s_wkv[wr][lane * 2]     = ax;
        s_wkv[wr][lane * 2 + 1] = ay;
        if (lane < TE_DIM) s_wkv[wr][F_DIM + lane] = at;
    }
    __syncthreads();

    // ---- P4: ao = V2 @ wkv + b2 ----
    gemv_rows(V2, B2, s_wkv, s_ao, tid);
    __syncthreads();

    // ---- P5: epilogue (wave per row, lane = k) ----
    {
        float p = s_ao[wr][lane] * mlp_w[lane];
        p = fmaf(s_ao[wr][lane + 64], mlp_w[lane + 64], p);
        if (lane < 32) p = fmaf(s_ao[wr][lane + 128], mlp_w[lane + 128], p);
        const float base = wave_sum(p) + mlp_b[0];

        float* ao = out_ao + (long)b * DD;
        ao[lane]      = s_ao[wr][lane];
        ao[lane + 64] = s_ao[wr][lane + 64];
        if (lane < 32) ao[lane + 128] = s_ao[wr][lane + 128];

        const float u = gumbel_u[(long)b * KK + lane];
        const float g = -logf(-logf(u + 1e-10f) + 1e-10f);
        const float z = aw + g;  // TAU = 1.0
        const float m = wave_max(z);
        const float e = expf(z - m);
        const float l = wave_sum(e);
        out_mask[(long)b * KK + lane] = (e / l > 0.2f) ? 1.0f : 0.0f;

        const float ew  = edge_weight[(long)b * KK + lane];
        const float val = fmaf(ew, mlp_w[DD], base);
        out_new[(long)b * KK + lane] = (val >= 0.f) ? val : 0.01f * val;
    }
}

extern "C" void kernel_launch(void* const* d_in, const int* in_sizes, int n_in,
                              void* d_out, int out_size, void* d_ws, size_t ws_size,
                              hipStream_t stream) {
    const float* x   = (const float*)d_in[0];
    const int*   tni = (const int*)d_in[1];
    const int*   tnt = (const int*)d_in[2];
    const int*   nid = (const int*)d_in[3];
    const int*   et  = (const int*)d_in[4];
    const float* ew  = (const float*)d_in[5];
    const float* gu  = (const float*)d_in[6];
    const float* tew = (const float*)d_in[7];
    const float* teb = (const float*)d_in[8];
    const float* ipw = (const float*)d_in[9];
    const float* ipb = (const float*)d_in[10];
    const float* ow  = (const float*)d_in[11];
    const float* ob  = (const float*)d_in[12];
    const float* mw  = (const float*)d_in[13];
    const float* mb  = (const float*)d_in[14];

    float* wsf = (float*)d_ws;

    float* out      = (float*)d_out;
    float* out_ao   = out;
    float* out_new  = out + (long)NB * DD;
    float* out_mask = out + (long)NB * DD + (long)NB * KK;

    setup_kernel<<<2 * DD + 3, 256, 0, stream>>>(ipw, ipb, ow, ob, wsf);

    structure_learner_kernel<<<NB / ROWS, 256, 0, stream>>>(
        x, tni, tnt, nid, et, ew, gu, tew, teb, mw, mb, wsf,
        out_ao, out_new, out_mask);
}